// Round 3
// baseline (164.806 us; speedup 1.0000x reference)
//
#include <hip/hip_runtime.h>
#include <math.h>

// Problem constants (match reference)
#define BB 4096
#define LL 128
#define DD 64

// Key facts exploited:
//  - mask is wave-uniform per row l: skip mu/feat gathers for masked rows
//    (contribution is exactly 0 unless ALL rows masked -> s_nm fallback).
//  - mu row values held in registers (v[32]) between q-pass and score-pass;
//    scores via 6-level shfl_xor butterfly -> no re-gather traffic.
//  - row ids / attn weights broadcast via __shfl(reg, j) (v_readlane),
//    so skip branches are SALU-only and loads pipeline.
__global__ __launch_bounds__(256, 6) void softmax_attn_cos_kernel(
    const int* __restrict__ ids_a, const int* __restrict__ mask_a,
    const int* __restrict__ ids_b, const int* __restrict__ mask_b,
    const float* __restrict__ mu_table, const float* __restrict__ feat_table,
    float* __restrict__ out)
{
    __shared__ int   s_ids[LL];
    __shared__ float s_m[LL];
    __shared__ float s_q[DD];
    __shared__ float s_part[4][DD];
    __shared__ float s_sc[LL];
    __shared__ float s_mean[2][DD];
    __shared__ float s_sum;
    __shared__ int   s_nm;

    const int tid   = threadIdx.x;
    const int d     = tid & 63;
    const int lsub  = tid >> 6;      // wave id 0..3
    const int lbase = lsub * 32;
    const int b     = blockIdx.x;

    for (int side = 0; side < 2; ++side) {
        const int* ids = side ? ids_b  : ids_a;
        const int* msk = side ? mask_b : mask_a;

        // ---- phase 1: ids + mask into LDS ----
        if (tid < LL) s_ids[tid] = ids[b * LL + tid];
        else          s_m[tid - LL] = (float)msk[b * LL + (tid - LL)];
        __syncthreads();

        // per-wave 32-bit row mask (uniform) + row ids in a register
        const unsigned long long bl =
            __ballot((d < 32) ? (s_m[lbase + (d & 31)] > 0.5f) : 0);
        const unsigned bm = (unsigned)bl;
        const int idv = s_ids[lbase + (d & 31)];

        // ---- phase 2: gather unmasked mu rows into registers (coalesced) ----
        float v[32];
        #pragma unroll
        for (int j = 0; j < 32; ++j) {
            v[j] = 0.f;
            if (bm & (1u << j)) {
                const int id = __shfl(idv, j, 64);
                v[j] = mu_table[(size_t)id * DD + d];
            }
        }
        float qacc = 0.f;
        #pragma unroll
        for (int j = 0; j < 32; ++j) qacc += v[j];   // m==1 exactly for kept rows
        s_part[lsub][d] = qacc;
        __syncthreads();

        // ---- q = masked mean, nm count (wave 0) ----
        if (tid < 64) {
            float mv = s_m[tid] + s_m[tid + 64];
            #pragma unroll
            for (int off = 32; off; off >>= 1) mv += __shfl_xor(mv, off, 64);
            if (tid == 0) s_nm = (int)(mv + 0.5f);
            const float denom = fmaxf(mv, 1.0f);
            s_q[d] = (s_part[0][d] + s_part[1][d] + s_part[2][d] + s_part[3][d]) / denom;
        }
        __syncthreads();

        // ---- phase 3: scores via butterfly reduction (no memory traffic) ----
        const float qd = s_q[d];
        #pragma unroll
        for (int j = 0; j < 32; ++j) {
            if (bm & (1u << j)) {
                float sc = v[j] * qd;
                #pragma unroll
                for (int off = 32; off; off >>= 1) sc += __shfl_xor(sc, off, 64);
                if (d == 0) s_sc[lbase + j] = sc;
            } else if (d == 0) {
                s_sc[lbase + j] = -1e9f;
            }
        }
        __syncthreads();

        // ---- phase 4: softmax over 128 scores (wave 0) ----
        if (tid < 64) {
            const float s1 = s_sc[tid], s2 = s_sc[tid + 64];
            float mx = fmaxf(s1, s2);
            #pragma unroll
            for (int off = 32; off; off >>= 1) mx = fmaxf(mx, __shfl_xor(mx, off, 64));
            const float e1 = expf(s1 - mx), e2 = expf(s2 - mx);
            s_sc[tid] = e1; s_sc[tid + 64] = e2;
            float sm = e1 + e2;
            #pragma unroll
            for (int off = 32; off; off >>= 1) sm += __shfl_xor(sm, off, 64);
            if (tid == 0) s_sum = sm;
        }
        __syncthreads();

        // ---- phase 5: attn-weighted feat gather, masked rows skipped ----
        const bool allm = (s_nm == 0);               // all-masked fallback (exact ref semantics)
        const float av = s_sc[lbase + (d & 31)];     // attn weights for this wave's rows
        #pragma unroll
        for (int j = 0; j < 32; ++j) {
            v[j] = 0.f;
            if (allm || (bm & (1u << j))) {
                const int id = __shfl(idv, j, 64);
                v[j] = feat_table[(size_t)id * DD + d];
            }
        }
        float oacc = 0.f;
        #pragma unroll
        for (int j = 0; j < 32; ++j)
            oacc = fmaf(v[j], __shfl(av, j, 64), oacc);  // v==0 for skipped rows
        s_part[lsub][d] = oacc;
        __syncthreads();
        if (tid < 64) {
            s_mean[side][d] =
                (s_part[0][d] + s_part[1][d] + s_part[2][d] + s_part[3][d]) / s_sum;
        }
        __syncthreads();
    }

    // ---- cosine similarity * 5 (wave 0) ----
    if (tid < 64) {
        const float a = s_mean[0][tid], c = s_mean[1][tid];
        float dt = a * c, na = a * a, nb = c * c;
        #pragma unroll
        for (int off = 32; off; off >>= 1) {
            dt += __shfl_xor(dt, off, 64);
            na += __shfl_xor(na, off, 64);
            nb += __shfl_xor(nb, off, 64);
        }
        if (tid == 0) {
            const float denom = fmaxf(sqrtf(na), 1e-8f) * fmaxf(sqrtf(nb), 1e-8f);
            out[b] = 5.0f * dt / denom;
        }
    }
}

extern "C" void kernel_launch(void* const* d_in, const int* in_sizes, int n_in,
                              void* d_out, int out_size, void* d_ws, size_t ws_size,
                              hipStream_t stream) {
    const int*   ids_a  = (const int*)d_in[0];
    const int*   mask_a = (const int*)d_in[1];
    const int*   ids_b  = (const int*)d_in[2];
    const int*   mask_b = (const int*)d_in[3];
    const float* mu     = (const float*)d_in[4];
    const float* feat   = (const float*)d_in[5];
    float* out = (float*)d_out;

    softmax_attn_cos_kernel<<<BB, 256, 0, stream>>>(
        ids_a, mask_a, ids_b, mask_b, mu, feat, out);
}

// Round 4
// 130.532 us; speedup vs baseline: 1.2626x; 1.2626x over previous
//
#include <hip/hip_runtime.h>
#include <math.h>

// Problem constants (match reference)
#define BB 4096
#define LL 128
#define DD 64

// Round-4 structure:
//  - waves 0-1 process side a, waves 2-3 side b (parallel sides -> half the
//    serial barrier chain, 2x independent memory parallelism per barrier gap)
//  - gathers are 4-rows-per-wave-iteration: lanes in groups of 16, each lane
//    loads a float4 -> 4x fewer gather instructions than row-per-iteration
//  - mask-skip on every gather pass (masked rows contribute exactly 0; the
//    all-masked fallback is handled via s_nm, matching jax uniform-softmax)
//  - no register arrays held across phases -> no scratch spill (round-3 bug)
__global__ __launch_bounds__(256, 8) void softmax_attn_cos_kernel(
    const int* __restrict__ ids_a, const int* __restrict__ mask_a,
    const int* __restrict__ ids_b, const int* __restrict__ mask_b,
    const float* __restrict__ mu_table, const float* __restrict__ feat_table,
    float* __restrict__ out)
{
    __shared__ int    s_ids[2][LL];
    __shared__ float  s_msk[2][LL];
    __shared__ float4 s_q[2][16];
    __shared__ float4 s_qp[2][2][16];
    __shared__ float  s_sc[2][LL];
    __shared__ float4 s_op[2][2][16];
    __shared__ float  s_mean[2][DD];
    __shared__ float  s_sum[2];
    __shared__ int    s_nm[2];

    const int tid  = threadIdx.x;
    const int lane = tid & 63;
    const int wave = tid >> 6;        // 0..3
    const int side = wave >> 1;       // 0: a, 1: b
    const int wsub = wave & 1;        // which half of the 128 rows
    const int grp  = lane >> 4;       // 0..3 row subgroup
    const int c4   = lane & 15;       // float4 column index
    const int b    = blockIdx.x;

    // ---- phase 1: ids + masks for both sides (each thread loads 1 id + 1 mask) ----
    {
        const int si = tid >> 7;          // waves 0-1 -> side 0, waves 2-3 -> side 1
        const int l  = tid & 127;
        const int* idp = si ? ids_b  : ids_a;
        const int* mp  = si ? mask_b : mask_a;
        s_ids[si][l] = idp[b * LL + l];
        s_msk[si][l] = (float)mp[b * LL + l];
    }
    __syncthreads();

    // ---- phase 2: masked mu accumulation, 4 rows / iteration ----
    {
        float4 qp = make_float4(0.f, 0.f, 0.f, 0.f);
        #pragma unroll
        for (int it = 0; it < 16; ++it) {
            const int r = wsub * 64 + it * 4 + grp;
            if (s_msk[side][r] > 0.5f) {
                const float4 f =
                    ((const float4*)(mu_table + (size_t)s_ids[side][r] * DD))[c4];
                qp.x += f.x; qp.y += f.y; qp.z += f.z; qp.w += f.w;
            }
        }
        // reduce the 4 row-groups (lanes with equal c4)
        #pragma unroll
        for (int off = 16; off <= 32; off <<= 1) {
            qp.x += __shfl_xor(qp.x, off, 64);
            qp.y += __shfl_xor(qp.y, off, 64);
            qp.z += __shfl_xor(qp.z, off, 64);
            qp.w += __shfl_xor(qp.w, off, 64);
        }
        if (lane < 16) s_qp[side][wsub][c4] = qp;
    }
    __syncthreads();

    // ---- q = masked mean + nm count (waves 0 and 1, one per side) ----
    if (tid < 128) {
        const int si = tid >> 6;
        const int dd = tid & 63;
        float mv = s_msk[si][dd] + s_msk[si][dd + 64];
        #pragma unroll
        for (int off = 32; off; off >>= 1) mv += __shfl_xor(mv, off, 64);
        if (dd == 0) s_nm[si] = (int)(mv + 0.5f);
        const float denom = fmaxf(mv, 1.0f);
        if (dd < 16) {
            float4 q0 = s_qp[si][0][dd], q1 = s_qp[si][1][dd];
            float4 q;
            q.x = (q0.x + q1.x) / denom; q.y = (q0.y + q1.y) / denom;
            q.z = (q0.z + q1.z) / denom; q.w = (q0.w + q1.w) / denom;
            s_q[si][dd] = q;
        }
    }
    __syncthreads();

    // ---- phase 3: scores, 4 rows / iteration, mu re-gather (L2-hot, skipped) ----
    {
        const float4 q4 = s_q[side][c4];
        #pragma unroll
        for (int it = 0; it < 16; ++it) {
            const int r = wsub * 64 + it * 4 + grp;
            float sc = -1e9f;
            if (s_msk[side][r] > 0.5f) {
                const float4 f =
                    ((const float4*)(mu_table + (size_t)s_ids[side][r] * DD))[c4];
                sc = f.x * q4.x + f.y * q4.y + f.z * q4.z + f.w * q4.w;
                #pragma unroll
                for (int off = 1; off <= 8; off <<= 1)
                    sc += __shfl_xor(sc, off, 64);   // reduce within 16-lane group
            }
            if (c4 == 0) s_sc[side][r] = sc;
        }
    }
    __syncthreads();

    // ---- phase 4: softmax per side (wave 0 for side a, wave 2 for side b) ----
    if (wsub == 0) {
        const float s1 = s_sc[side][lane], s2 = s_sc[side][lane + 64];
        float mx = fmaxf(s1, s2);
        #pragma unroll
        for (int off = 32; off; off >>= 1) mx = fmaxf(mx, __shfl_xor(mx, off, 64));
        const float e1 = expf(s1 - mx), e2 = expf(s2 - mx);
        s_sc[side][lane] = e1; s_sc[side][lane + 64] = e2;
        float sm = e1 + e2;
        #pragma unroll
        for (int off = 32; off; off >>= 1) sm += __shfl_xor(sm, off, 64);
        if (lane == 0) s_sum[side] = sm;
    }
    __syncthreads();

    // ---- phase 5: attn-weighted feat, 4 rows / iteration, mask-skip ----
    {
        const bool allm = (s_nm[side] == 0);
        float4 op = make_float4(0.f, 0.f, 0.f, 0.f);
        #pragma unroll
        for (int it = 0; it < 16; ++it) {
            const int r = wsub * 64 + it * 4 + grp;
            if (allm || s_msk[side][r] > 0.5f) {
                const float w = s_sc[side][r];
                const float4 f =
                    ((const float4*)(feat_table + (size_t)s_ids[side][r] * DD))[c4];
                op.x = fmaf(f.x, w, op.x); op.y = fmaf(f.y, w, op.y);
                op.z = fmaf(f.z, w, op.z); op.w = fmaf(f.w, w, op.w);
            }
        }
        #pragma unroll
        for (int off = 16; off <= 32; off <<= 1) {
            op.x += __shfl_xor(op.x, off, 64);
            op.y += __shfl_xor(op.y, off, 64);
            op.z += __shfl_xor(op.z, off, 64);
            op.w += __shfl_xor(op.w, off, 64);
        }
        if (lane < 16) s_op[side][wsub][c4] = op;
    }
    __syncthreads();

    // ---- combine halves -> mean vectors ----
    if (tid < 32) {
        const int si = tid >> 4, cc = tid & 15;
        const float inv = 1.0f / s_sum[si];
        float4 o0 = s_op[si][0][cc], o1 = s_op[si][1][cc];
        float4 o;
        o.x = (o0.x + o1.x) * inv; o.y = (o0.y + o1.y) * inv;
        o.z = (o0.z + o1.z) * inv; o.w = (o0.w + o1.w) * inv;
        ((float4*)&s_mean[si][0])[cc] = o;
    }
    __syncthreads();

    // ---- cosine similarity * 5 (wave 0) ----
    if (tid < 64) {
        const float a = s_mean[0][tid], c = s_mean[1][tid];
        float dt = a * c, na = a * a, nb = c * c;
        #pragma unroll
        for (int off = 32; off; off >>= 1) {
            dt += __shfl_xor(dt, off, 64);
            na += __shfl_xor(na, off, 64);
            nb += __shfl_xor(nb, off, 64);
        }
        if (tid == 0) {
            const float denom = fmaxf(sqrtf(na), 1e-8f) * fmaxf(sqrtf(nb), 1e-8f);
            out[b] = 5.0f * dt / denom;
        }
    }
}

extern "C" void kernel_launch(void* const* d_in, const int* in_sizes, int n_in,
                              void* d_out, int out_size, void* d_ws, size_t ws_size,
                              hipStream_t stream) {
    const int*   ids_a  = (const int*)d_in[0];
    const int*   mask_a = (const int*)d_in[1];
    const int*   ids_b  = (const int*)d_in[2];
    const int*   mask_b = (const int*)d_in[3];
    const float* mu     = (const float*)d_in[4];
    const float* feat   = (const float*)d_in[5];
    float* out = (float*)d_out;

    softmax_attn_cos_kernel<<<BB, 256, 0, stream>>>(
        ids_a, mask_a, ids_b, mask_b, mu, feat, out);
}

// Round 5
// 129.430 us; speedup vs baseline: 1.2733x; 1.0085x over previous
//
#include <hip/hip_runtime.h>
#include <math.h>

// Problem constants (match reference)
#define BB 4096
#define LL 128
#define DD 64

// Round-5 structure (delta vs round 4):
//  - mu rows held in registers (float4 v[16] = 64 VGPRs) across phases 2-3:
//    phase 3 is pure VALU, no re-gather  -> 3 gather passes become 2
//  - v[] reused for feat: loads issued during phase 3 (overlap with score
//    reductions + the softmax barrier drain), consumed from registers in ph 5
//  - per-lane `kept` bitmask carried from phase 2 (no LDS mask re-reads)
//  - __launch_bounds__(256,4): 128-VGPR budget, spill-proof by construction
__global__ __launch_bounds__(256, 4) void softmax_attn_cos_kernel(
    const int* __restrict__ ids_a, const int* __restrict__ mask_a,
    const int* __restrict__ ids_b, const int* __restrict__ mask_b,
    const float* __restrict__ mu_table, const float* __restrict__ feat_table,
    float* __restrict__ out)
{
    __shared__ int    s_ids[2][LL];
    __shared__ float  s_msk[2][LL];
    __shared__ float4 s_q[2][16];
    __shared__ float4 s_qp[2][2][16];
    __shared__ float  s_sc[2][LL];
    __shared__ float4 s_op[2][2][16];
    __shared__ float  s_mean[2][DD];
    __shared__ float  s_sum[2];
    __shared__ int    s_nm[2];

    const int tid  = threadIdx.x;
    const int lane = tid & 63;
    const int wave = tid >> 6;        // 0..3
    const int side = wave >> 1;       // 0: a, 1: b
    const int wsub = wave & 1;        // which half of the 128 rows
    const int grp  = lane >> 4;       // 0..3 row subgroup
    const int c4   = lane & 15;       // float4 column index
    const int b    = blockIdx.x;

    // ---- phase 1: ids + masks for both sides ----
    {
        const int si = tid >> 7;
        const int l  = tid & 127;
        const int* idp = si ? ids_b  : ids_a;
        const int* mp  = si ? mask_b : mask_a;
        s_ids[si][l] = idp[b * LL + l];
        s_msk[si][l] = (float)mp[b * LL + l];
    }
    __syncthreads();

    // ---- phase 2: gather unmasked mu rows into registers, accumulate q partials ----
    float4 v[16];
    unsigned kept = 0;
    {
        float4 qp = make_float4(0.f, 0.f, 0.f, 0.f);
        #pragma unroll
        for (int it = 0; it < 16; ++it) {
            const int r = wsub * 64 + it * 4 + grp;
            v[it] = make_float4(0.f, 0.f, 0.f, 0.f);
            if (s_msk[side][r] > 0.5f) {
                kept |= (1u << it);
                v[it] = ((const float4*)(mu_table + (size_t)s_ids[side][r] * DD))[c4];
                qp.x += v[it].x; qp.y += v[it].y; qp.z += v[it].z; qp.w += v[it].w;
            }
        }
        #pragma unroll
        for (int off = 16; off <= 32; off <<= 1) {
            qp.x += __shfl_xor(qp.x, off, 64);
            qp.y += __shfl_xor(qp.y, off, 64);
            qp.z += __shfl_xor(qp.z, off, 64);
            qp.w += __shfl_xor(qp.w, off, 64);
        }
        if (lane < 16) s_qp[side][wsub][c4] = qp;
    }
    __syncthreads();

    // ---- q = masked mean + nm count (waves 0/1, one per side) ----
    if (tid < 128) {
        const int si = tid >> 6;
        const int dd = tid & 63;
        float mv = s_msk[si][dd] + s_msk[si][dd + 64];
        #pragma unroll
        for (int off = 32; off; off >>= 1) mv += __shfl_xor(mv, off, 64);
        if (dd == 0) s_nm[si] = (int)(mv + 0.5f);
        const float denom = fmaxf(mv, 1.0f);
        if (dd < 16) {
            float4 q0 = s_qp[si][0][dd], q1 = s_qp[si][1][dd];
            float4 q;
            q.x = (q0.x + q1.x) / denom; q.y = (q0.y + q1.y) / denom;
            q.z = (q0.z + q1.z) / denom; q.w = (q0.w + q1.w) / denom;
            s_q[si][dd] = q;
        }
    }
    __syncthreads();

    // ---- phase 3: scores from registers (no loads) + issue feat loads into v[] ----
    {
        const float4 q4  = s_q[side][c4];
        const bool  allm = (s_nm[side] == 0);
        #pragma unroll
        for (int it = 0; it < 16; ++it) {
            const int r = wsub * 64 + it * 4 + grp;
            const bool k = (kept >> it) & 1u;
            float sc = v[it].x * q4.x + v[it].y * q4.y
                     + v[it].z * q4.z + v[it].w * q4.w;
            #pragma unroll
            for (int off = 1; off <= 8; off <<= 1)
                sc += __shfl_xor(sc, off, 64);       // reduce within 16-lane group
            if (c4 == 0) s_sc[side][r] = k ? sc : -1e9f;
            // mu value consumed -> overwrite with feat (loads overlap reductions)
            v[it] = make_float4(0.f, 0.f, 0.f, 0.f);
            if (allm || k)
                v[it] = ((const float4*)(feat_table + (size_t)s_ids[side][r] * DD))[c4];
        }
    }
    __syncthreads();

    // ---- phase 4: softmax per side (waves with wsub==0) ----
    if (wsub == 0) {
        const float s1 = s_sc[side][lane], s2 = s_sc[side][lane + 64];
        float mx = fmaxf(s1, s2);
        #pragma unroll
        for (int off = 32; off; off >>= 1) mx = fmaxf(mx, __shfl_xor(mx, off, 64));
        const float e1 = expf(s1 - mx), e2 = expf(s2 - mx);
        s_sc[side][lane] = e1; s_sc[side][lane + 64] = e2;
        float sm = e1 + e2;
        #pragma unroll
        for (int off = 32; off; off >>= 1) sm += __shfl_xor(sm, off, 64);
        if (lane == 0) s_sum[side] = sm;
    }
    __syncthreads();

    // ---- phase 5: attn-weighted sum from registers ----
    {
        float4 op = make_float4(0.f, 0.f, 0.f, 0.f);
        #pragma unroll
        for (int it = 0; it < 16; ++it) {
            const int r = wsub * 64 + it * 4 + grp;
            const float w = s_sc[side][r];           // v[it]==0 for skipped rows
            op.x = fmaf(v[it].x, w, op.x); op.y = fmaf(v[it].y, w, op.y);
            op.z = fmaf(v[it].z, w, op.z); op.w = fmaf(v[it].w, w, op.w);
        }
        #pragma unroll
        for (int off = 16; off <= 32; off <<= 1) {
            op.x += __shfl_xor(op.x, off, 64);
            op.y += __shfl_xor(op.y, off, 64);
            op.z += __shfl_xor(op.z, off, 64);
            op.w += __shfl_xor(op.w, off, 64);
        }
        if (lane < 16) s_op[side][wsub][c4] = op;
    }
    __syncthreads();

    // ---- combine halves -> mean vectors ----
    if (tid < 32) {
        const int si = tid >> 4, cc = tid & 15;
        const float inv = 1.0f / s_sum[si];
        float4 o0 = s_op[si][0][cc], o1 = s_op[si][1][cc];
        float4 o;
        o.x = (o0.x + o1.x) * inv; o.y = (o0.y + o1.y) * inv;
        o.z = (o0.z + o1.z) * inv; o.w = (o0.w + o1.w) * inv;
        ((float4*)&s_mean[si][0])[cc] = o;
    }
    __syncthreads();

    // ---- cosine similarity * 5 (wave 0) ----
    if (tid < 64) {
        const float a = s_mean[0][tid], c = s_mean[1][tid];
        float dt = a * c, na = a * a, nb = c * c;
        #pragma unroll
        for (int off = 32; off; off >>= 1) {
            dt += __shfl_xor(dt, off, 64);
            na += __shfl_xor(na, off, 64);
            nb += __shfl_xor(nb, off, 64);
        }
        if (tid == 0) {
            const float denom = fmaxf(sqrtf(na), 1e-8f) * fmaxf(sqrtf(nb), 1e-8f);
            out[b] = 5.0f * dt / denom;
        }
    }
}

extern "C" void kernel_launch(void* const* d_in, const int* in_sizes, int n_in,
                              void* d_out, int out_size, void* d_ws, size_t ws_size,
                              hipStream_t stream) {
    const int*   ids_a  = (const int*)d_in[0];
    const int*   mask_a = (const int*)d_in[1];
    const int*   ids_b  = (const int*)d_in[2];
    const int*   mask_b = (const int*)d_in[3];
    const float* mu     = (const float*)d_in[4];
    const float* feat   = (const float*)d_in[5];
    float* out = (float*)d_out;

    softmax_attn_cos_kernel<<<BB, 256, 0, stream>>>(
        ids_a, mask_a, ids_b, mask_b, mu, feat, out);
}